// Round 5
// baseline (289.424 us; speedup 1.0000x reference)
//
#include <hip/hip_runtime.h>
#include <hip/hip_bf16.h>
#include <stdint.h>
#include <math.h>

#define NN 16384
#define DD 256
#define MARGIN_F 0.2f

typedef __attribute__((ext_vector_type(8))) short bf16x8;
typedef __attribute__((ext_vector_type(4))) float f32x4;

__device__ inline short f2bf(float f) {
    __hip_bfloat16 h = __float2bfloat16(f);
    return *reinterpret_cast<short*>(&h);
}

// float atomic max via int/uint atomics (init = -inf)
__device__ inline void atomicMaxF(float* addr, float val) {
    if (val >= 0.0f) {
        atomicMax(reinterpret_cast<int*>(addr), __float_as_int(val));
    } else {
        atomicMin(reinterpret_cast<unsigned int*>(addr), __float_as_uint(val));
    }
}

// ---------------- fused prep: f32->bf16 + diag + init maxes ----------------
// 4 rows per 256-thread block (one wave per row)
__global__ __launch_bounds__(256) void fused_prep_kernel(
    const float* __restrict__ imgs, const float* __restrict__ caps,
    short* __restrict__ imgsb, short* __restrict__ capsb,
    float* __restrict__ diag, float* __restrict__ rowmax,
    float* __restrict__ colmax) {
    const int i = (blockIdx.x << 2) + (threadIdx.x >> 6);
    const int l = threadIdx.x & 63;  // covers 256 elems as float4
    const float4* a4 = reinterpret_cast<const float4*>(imgs + (size_t)i * DD);
    const float4* b4 = reinterpret_cast<const float4*>(caps + (size_t)i * DD);
    float4 av = a4[l];
    float4 bv = b4[l];
    short4 as, bs;
    as.x = f2bf(av.x); as.y = f2bf(av.y); as.z = f2bf(av.z); as.w = f2bf(av.w);
    bs.x = f2bf(bv.x); bs.y = f2bf(bv.y); bs.z = f2bf(bv.z); bs.w = f2bf(bv.w);
    reinterpret_cast<short4*>(imgsb + (size_t)i * DD)[l] = as;
    reinterpret_cast<short4*>(capsb + (size_t)i * DD)[l] = bs;
    float s = av.x * bv.x + av.y * bv.y + av.z * bv.z + av.w * bv.w;
    #pragma unroll
    for (int off = 32; off > 0; off >>= 1) s += __shfl_down(s, off);
    if (l == 0) {
        diag[i] = s;
        rowmax[i] = -INFINITY;
        colmax[i] = -INFINITY;
    }
}

// ---------------- main: all-register strip kernel, zero LDS / zero barriers -
// 512 blocks = 128 row-panels x 4 col-strips. A panel fragments live in VGPRs
// (af[4][8] = 128 regs/lane). B fragments load global->VGPR directly from L2;
// each b[ks] is reloaded with the NEXT chunk right after its last MFMA use,
// so ~7 ks-steps of MFMA cover the L2 latency. No __shared__, no barriers.
// XCD mapping: bid&7 selects strip pair -> each XCD's L2 holds one 2MB strip.
__global__ __launch_bounds__(256, 2) void score_max_kernel(
    const short* __restrict__ imgsb, const short* __restrict__ capsb,
    const float* __restrict__ diag,
    float* __restrict__ rowmax, float* __restrict__ colmax) {

    const int bid   = blockIdx.x;
    const int xj    = bid & 7;                      // = XCD id (round-robin)
    const int strip = xj >> 1;                      // 2 XCDs per strip
    const int panel = ((bid >> 3) << 1) | (xj & 1);
    const int brow  = panel << 7;    // 128-row panel
    const int scol  = strip << 12;   // 4096-col strip

    const int t    = threadIdx.x;
    const int wid  = t >> 6;
    const int lane = t & 63;
    const int wr   = wid >> 1;   // 0..1: 64-row half
    const int wc   = wid & 1;    // 0..1: 32-col half of 64-col chunk
    const int rg   = lane >> 4;  // 0..3
    const int cl   = lane & 15;  // 0..15

    // ---- A fragments direct from global: af[m][ks], 128 regs ----
    bf16x8 af[4][8];
    #pragma unroll
    for (int m = 0; m < 4; ++m) {
        const short* pa =
            imgsb + (size_t)(brow + wr * 64 + m * 16 + cl) * DD + rg * 8;
        #pragma unroll
        for (int ks = 0; ks < 8; ++ks)
            af[m][ks] = *reinterpret_cast<const bf16x8*>(pa + ks * 32);
    }

    // ---- B base pointers (this lane's col rows) ----
    const short* pb0 = capsb + (size_t)(scol + wc * 32 + cl) * DD + rg * 8;
    const short* pb1 = pb0 + 16 * DD;

    // prologue: load chunk h=0
    bf16x8 b0[8], b1[8];
    #pragma unroll
    for (int ks = 0; ks < 8; ++ks) {
        b0[ks] = *reinterpret_cast<const bf16x8*>(pb0 + ks * 32);
        b1[ks] = *reinterpret_cast<const bf16x8*>(pb1 + ks * 32);
    }

    float rmx[4][4];
    #pragma unroll
    for (int m = 0; m < 4; ++m)
        #pragma unroll
        for (int r = 0; r < 4; ++r) rmx[m][r] = -INFINITY;

    for (int h = 0; h < 64; ++h) {
        const int cb = scol + (h << 6);
        const int hn = (h < 63) ? h + 1 : h;     // clamp: dead reload at tail
        const short* nx0 = pb0 + ((size_t)hn << 14);   // 64 rows * 256 elems
        const short* nx1 = pb1 + ((size_t)hn << 14);

        f32x4 acc[4][2];
        #pragma unroll
        for (int m = 0; m < 4; ++m) {
            acc[m][0] = (f32x4){0.f, 0.f, 0.f, 0.f};
            acc[m][1] = (f32x4){0.f, 0.f, 0.f, 0.f};
        }

        #pragma unroll
        for (int ks = 0; ks < 8; ++ks) {
            #pragma unroll
            for (int m = 0; m < 4; ++m)
                acc[m][0] = __builtin_amdgcn_mfma_f32_16x16x32_bf16(
                    af[m][ks], b0[ks], acc[m][0], 0, 0, 0);
            #pragma unroll
            for (int m = 0; m < 4; ++m)
                acc[m][1] = __builtin_amdgcn_mfma_f32_16x16x32_bf16(
                    af[m][ks], b1[ks], acc[m][1], 0, 0, 0);
            // reload this slot with next chunk (WAR: MFMAs above already
            // issued; loads return long before next h's first use)
            b0[ks] = *reinterpret_cast<const bf16x8*>(nx0 + ks * 32);
            b1[ks] = *reinterpret_cast<const bf16x8*>(nx1 + ks * 32);
        }

        // ---- diagonal fix (at most 2 chunks per block) ----
        if (cb < brow + 128 && cb + 64 > brow) {
            #pragma unroll
            for (int m = 0; m < 4; ++m)
                #pragma unroll
                for (int r = 0; r < 4; ++r) {
                    const int i = brow + wr * 64 + m * 16 + (rg << 2) + r;
                    const int d = i - cb - wc * 32;
                    #pragma unroll
                    for (int n = 0; n < 2; ++n)
                        if (d == n * 16 + cl) acc[m][n][r] = -diag[i];
                }
        }

        // ---- running row-max (registers, no shuffles) ----
        #pragma unroll
        for (int m = 0; m < 4; ++m)
            #pragma unroll
            for (int r = 0; r < 4; ++r)
                rmx[m][r] = fmaxf(rmx[m][r],
                                  fmaxf(acc[m][0][r], acc[m][1][r]));

        // ---- col-max for this chunk ----
        #pragma unroll
        for (int n = 0; n < 2; ++n) {
            float v = acc[0][n][0];
            #pragma unroll
            for (int m = 0; m < 4; ++m)
                #pragma unroll
                for (int r = 0; r < 4; ++r)
                    v = fmaxf(v, acc[m][n][r]);
            v = fmaxf(v, __shfl_xor(v, 16));
            v = fmaxf(v, __shfl_xor(v, 32));
            if (rg == 0)
                atomicMaxF(&colmax[cb + wc * 32 + n * 16 + cl], v);
        }
    }

    // ---- row-max writeout (once per block) ----
    #pragma unroll
    for (int m = 0; m < 4; ++m)
        #pragma unroll
        for (int r = 0; r < 4; ++r) {
            float v = rmx[m][r];
            v = fmaxf(v, __shfl_xor(v, 1));
            v = fmaxf(v, __shfl_xor(v, 2));
            v = fmaxf(v, __shfl_xor(v, 4));
            v = fmaxf(v, __shfl_xor(v, 8));
            if (cl == 0)
                atomicMaxF(&rowmax[brow + wr * 64 + m * 16 + (rg << 2) + r], v);
        }
}

// ---------------- finalize: hinge + total sum ----------------
__global__ void finalize_kernel(const float* __restrict__ diag,
                                const float* __restrict__ rowmax,
                                const float* __restrict__ colmax,
                                float* __restrict__ out) {
    __shared__ float red[256];
    int t = threadIdx.x;
    float s = 0.f;
    for (int idx = t; idx < 2 * NN; idx += 256) {
        int i = idx & (NN - 1);
        float mx = (idx < NN) ? colmax[i] : rowmax[i];
        s += fmaxf(mx + (MARGIN_F - diag[i]), 0.f);
    }
    red[t] = s;
    __syncthreads();
    for (int off = 128; off > 0; off >>= 1) {
        if (t < off) red[t] += red[t + off];
        __syncthreads();
    }
    if (t == 0) out[0] = red[0];
}

extern "C" void kernel_launch(void* const* d_in, const int* in_sizes, int n_in,
                              void* d_out, int out_size, void* d_ws, size_t ws_size,
                              hipStream_t stream) {
    const float* imgs = reinterpret_cast<const float*>(d_in[0]);
    const float* caps = reinterpret_cast<const float*>(d_in[1]);

    float* diag   = reinterpret_cast<float*>(d_ws);
    float* rowmax = diag + NN;
    float* colmax = rowmax + NN;
    short* imgsb  = reinterpret_cast<short*>(colmax + NN);
    short* capsb  = imgsb + (size_t)NN * DD;

    fused_prep_kernel<<<NN / 4, 256, 0, stream>>>(imgs, caps, imgsb, capsb,
                                                  diag, rowmax, colmax);

    score_max_kernel<<<512, 256, 0, stream>>>(imgsb, capsb, diag,
                                              rowmax, colmax);

    finalize_kernel<<<1, 256, 0, stream>>>(diag, rowmax, colmax,
                                           reinterpret_cast<float*>(d_out));
}

// Round 6
// 171.176 us; speedup vs baseline: 1.6908x; 1.6908x over previous
//
#include <hip/hip_runtime.h>
#include <hip/hip_bf16.h>
#include <stdint.h>
#include <math.h>

#define NN 16384
#define DD 256
#define MARGIN_F 0.2f

typedef __attribute__((ext_vector_type(8))) short bf16x8;
typedef __attribute__((ext_vector_type(4))) float f32x4;

__device__ inline short f2bf(float f) {
    __hip_bfloat16 h = __float2bfloat16(f);
    return *reinterpret_cast<short*>(&h);
}

// monotone order-preserving float<->uint key (max via unsigned atomicMax)
__device__ inline unsigned fkey(float f) {
    unsigned b = __float_as_uint(f);
    return (b & 0x80000000u) ? ~b : (b | 0x80000000u);
}
__device__ inline float fdec(unsigned k) {
    return __uint_as_float((k & 0x80000000u) ? (k ^ 0x80000000u) : ~k);
}
#define NEG_INF_KEY 0x007FFFFFu   // fkey(-inf)

__device__ inline void gload16(const void* g, void* l) {
    __builtin_amdgcn_global_load_lds(
        (const __attribute__((address_space(1))) void*)g,
        (__attribute__((address_space(3))) void*)l, 16, 0, 0);
}

// ---------------- fused prep: f32->bf16 + diag + init maxes ----------------
__global__ __launch_bounds__(256) void fused_prep_kernel(
    const float* __restrict__ imgs, const float* __restrict__ caps,
    short* __restrict__ imgsb, short* __restrict__ capsb,
    float* __restrict__ diag, unsigned* __restrict__ rowmax,
    unsigned* __restrict__ colmax) {
    const int i = (blockIdx.x << 2) + (threadIdx.x >> 6);
    const int l = threadIdx.x & 63;
    const float4* a4 = reinterpret_cast<const float4*>(imgs + (size_t)i * DD);
    const float4* b4 = reinterpret_cast<const float4*>(caps + (size_t)i * DD);
    float4 av = a4[l];
    float4 bv = b4[l];
    short4 as, bs;
    as.x = f2bf(av.x); as.y = f2bf(av.y); as.z = f2bf(av.z); as.w = f2bf(av.w);
    bs.x = f2bf(bv.x); bs.y = f2bf(bv.y); bs.z = f2bf(bv.z); bs.w = f2bf(bv.w);
    reinterpret_cast<short4*>(imgsb + (size_t)i * DD)[l] = as;
    reinterpret_cast<short4*>(capsb + (size_t)i * DD)[l] = bs;
    float s = av.x * bv.x + av.y * bv.y + av.z * bv.z + av.w * bv.w;
    #pragma unroll
    for (int off = 32; off > 0; off >>= 1) s += __shfl_down(s, off);
    if (l == 0) {
        diag[i] = s;
        rowmax[i] = NEG_INF_KEY;
        colmax[i] = NEG_INF_KEY;
    }
}

// ---------------- main: A-resident strip kernel, 4-phase schedule ----------
// 512 blocks = 128 row-panels x 4 col-strips. A panel (128x256) -> registers.
// B: 64-col chunks double-buffered in LDS; each chunk processed in 4 phases:
//   {4x ds_read_b128 | 4x stage-gload} -> barrier -> lgkmcnt(0) ->
//   setprio(1) 16x MFMA setprio(0) -> [vmcnt(0) at p==3] -> barrier
// colmax kept as key-encoded LDS maxes, flushed once per block.
__global__ __launch_bounds__(256, 2) void score_max_kernel(
    const short* __restrict__ imgsb, const short* __restrict__ capsb,
    const float* __restrict__ diag,
    unsigned* __restrict__ rowmax, unsigned* __restrict__ colmax) {

    __shared__ char lds[81920];   // [0,64K): A then 2x32KB B bufs; [64K,80K): colmax keys
    unsigned* clds = reinterpret_cast<unsigned*>(lds + 65536);

    const int bid   = blockIdx.x;
    const int panel = bid >> 2;
    const int strip = bid & 3;
    const int brow  = panel << 7;
    const int scol  = strip << 12;

    const int t    = threadIdx.x;
    const int wid  = t >> 6;
    const int lane = t & 63;
    const int wr   = wid >> 1;
    const int wc   = wid & 1;
    const int rg   = lane >> 4;
    const int cl   = lane & 15;

    // ---- init colmax keys ----
    #pragma unroll
    for (int i = 0; i < 16; ++i) clds[t + (i << 8)] = NEG_INF_KEY;

    // ---- stage A panel (64KB), chunk-swizzled ----
    {
        const int cs = t & 31;
        const int r0 = t >> 5;
        const int co = ((cs ^ (r0 & 7)) << 3);
        const short* src = imgsb + (((size_t)(brow + r0)) << 8) + co;
        #pragma unroll
        for (int i = 0; i < 16; ++i)
            gload16(src + ((size_t)i << 11), lds + t * 16 + i * 4096);
    }
    __syncthreads();

    // ---- A fragments to registers: af[m][ks] ----
    bf16x8 af[4][8];
    #pragma unroll
    for (int m = 0; m < 4; ++m) {
        const int row = wr * 64 + m * 16 + cl;
        const char* rb = lds + row * 512;
        const int sw = row & 7;
        #pragma unroll
        for (int ks = 0; ks < 8; ++ks) {
            const int k8 = (ks << 2) + rg;
            af[m][ks] = *reinterpret_cast<const bf16x8*>(rb + ((k8 ^ sw) << 4));
        }
    }
    __syncthreads();   // done reading A before B overwrites

    // ---- B staging geometry ----
    const int br0 = t >> 5;
    const int bco = (((t & 31) ^ (br0 & 7)) << 3);

    // prologue: stage chunk h=0 into buf0
    {
        const short* s_ = capsb + (((size_t)(scol + br0)) << 8) + bco;
        #pragma unroll
        for (int i = 0; i < 8; ++i)
            gload16(s_ + ((size_t)i << 11), lds + t * 16 + i * 4096);
    }
    __syncthreads();   // full drain; buf0 ready

    float rmx[4][4];
    #pragma unroll
    for (int m = 0; m < 4; ++m)
        #pragma unroll
        for (int r = 0; r < 4; ++r) rmx[m][r] = -INFINITY;

    const int rr0 = wc * 32 + cl;       // B row for n=0
    const int rr1 = rr0 + 16;           // B row for n=1

    for (int h = 0; h < 64; ++h) {
        const int cb = scol + (h << 6);
        const char* cur = lds + ((h & 1) << 15);
        char* nxt = lds + (((h + 1) & 1) << 15);
        const short* nsrc = capsb + (((size_t)(cb + 64 + br0)) << 8) + bco;

        f32x4 acc[4][2];
        #pragma unroll
        for (int m = 0; m < 4; ++m) {
            acc[m][0] = (f32x4){0.f, 0.f, 0.f, 0.f};
            acc[m][1] = (f32x4){0.f, 0.f, 0.f, 0.f};
        }

        #pragma unroll
        for (int p = 0; p < 4; ++p) {
            // ds_reads for ks = 2p, 2p+1
            const int k80 = (p << 3) + rg;       // (2p)*4 + rg
            const int k81 = k80 + 4;
            bf16x8 b00 = *reinterpret_cast<const bf16x8*>(
                cur + rr0 * 512 + ((k80 ^ (rr0 & 7)) << 4));
            bf16x8 b10 = *reinterpret_cast<const bf16x8*>(
                cur + rr1 * 512 + ((k80 ^ (rr1 & 7)) << 4));
            bf16x8 b01 = *reinterpret_cast<const bf16x8*>(
                cur + rr0 * 512 + ((k81 ^ (rr0 & 7)) << 4));
            bf16x8 b11 = *reinterpret_cast<const bf16x8*>(
                cur + rr1 * 512 + ((k81 ^ (rr1 & 7)) << 4));

            // stage next chunk: 4 gloads in p=0, 4 in p=1
            if (p < 2 && h < 63) {
                #pragma unroll
                for (int i = 0; i < 4; ++i) {
                    const int ii = (p << 2) + i;
                    gload16(nsrc + ((size_t)ii << 11),
                            nxt + t * 16 + ii * 4096);
                }
            }

            __builtin_amdgcn_s_barrier();
            asm volatile("s_waitcnt lgkmcnt(0)" ::: "memory");
            __builtin_amdgcn_sched_barrier(0);
            __builtin_amdgcn_s_setprio(1);
            #pragma unroll
            for (int m = 0; m < 4; ++m)
                acc[m][0] = __builtin_amdgcn_mfma_f32_16x16x32_bf16(
                    af[m][2 * p], b00, acc[m][0], 0, 0, 0);
            #pragma unroll
            for (int m = 0; m < 4; ++m)
                acc[m][1] = __builtin_amdgcn_mfma_f32_16x16x32_bf16(
                    af[m][2 * p], b10, acc[m][1], 0, 0, 0);
            #pragma unroll
            for (int m = 0; m < 4; ++m)
                acc[m][0] = __builtin_amdgcn_mfma_f32_16x16x32_bf16(
                    af[m][2 * p + 1], b01, acc[m][0], 0, 0, 0);
            #pragma unroll
            for (int m = 0; m < 4; ++m)
                acc[m][1] = __builtin_amdgcn_mfma_f32_16x16x32_bf16(
                    af[m][2 * p + 1], b11, acc[m][1], 0, 0, 0);
            __builtin_amdgcn_s_setprio(0);
            if (p == 3) {
                // drain stage(h+1) (in flight ~3 phases) before next h reads
                asm volatile("s_waitcnt vmcnt(0)" ::: "memory");
            }
            __builtin_amdgcn_s_barrier();
        }

        // ---- diagonal fix (at most 2 chunks per block) ----
        if (cb < brow + 128 && cb + 64 > brow) {
            #pragma unroll
            for (int m = 0; m < 4; ++m)
                #pragma unroll
                for (int r = 0; r < 4; ++r) {
                    const int i = brow + wr * 64 + m * 16 + (rg << 2) + r;
                    const int d = i - cb - wc * 32;
                    #pragma unroll
                    for (int n = 0; n < 2; ++n)
                        if (d == n * 16 + cl) acc[m][n][r] = -diag[i];
                }
        }

        // ---- running row-max (registers) ----
        #pragma unroll
        for (int m = 0; m < 4; ++m)
            #pragma unroll
            for (int r = 0; r < 4; ++r)
                rmx[m][r] = fmaxf(rmx[m][r],
                                  fmaxf(acc[m][0][r], acc[m][1][r]));

        // ---- col-max -> LDS keys ----
        #pragma unroll
        for (int n = 0; n < 2; ++n) {
            float v = acc[0][n][0];
            #pragma unroll
            for (int m = 0; m < 4; ++m)
                #pragma unroll
                for (int r = 0; r < 4; ++r)
                    v = fmaxf(v, acc[m][n][r]);
            v = fmaxf(v, __shfl_xor(v, 16));
            v = fmaxf(v, __shfl_xor(v, 32));
            if (rg == 0)
                atomicMax(&clds[(h << 6) + wc * 32 + n * 16 + cl], fkey(v));
        }
    }

    // ---- flush colmax keys to global ----
    __syncthreads();
    #pragma unroll
    for (int i = 0; i < 16; ++i) {
        const int c = t + (i << 8);
        atomicMax(&colmax[scol + c], clds[c]);
    }

    // ---- row-max writeout ----
    #pragma unroll
    for (int m = 0; m < 4; ++m)
        #pragma unroll
        for (int r = 0; r < 4; ++r) {
            float v = rmx[m][r];
            v = fmaxf(v, __shfl_xor(v, 1));
            v = fmaxf(v, __shfl_xor(v, 2));
            v = fmaxf(v, __shfl_xor(v, 4));
            v = fmaxf(v, __shfl_xor(v, 8));
            if (cl == 0)
                atomicMax(&rowmax[brow + wr * 64 + m * 16 + (rg << 2) + r],
                          fkey(v));
        }
}

// ---------------- finalize: hinge + total sum ----------------
__global__ void finalize_kernel(const float* __restrict__ diag,
                                const unsigned* __restrict__ rowmax,
                                const unsigned* __restrict__ colmax,
                                float* __restrict__ out) {
    __shared__ float red[256];
    int t = threadIdx.x;
    float s = 0.f;
    for (int idx = t; idx < 2 * NN; idx += 256) {
        int i = idx & (NN - 1);
        float mx = fdec((idx < NN) ? colmax[i] : rowmax[i]);
        s += fmaxf(mx + (MARGIN_F - diag[i]), 0.f);
    }
    red[t] = s;
    __syncthreads();
    for (int off = 128; off > 0; off >>= 1) {
        if (t < off) red[t] += red[t + off];
        __syncthreads();
    }
    if (t == 0) out[0] = red[0];
}

extern "C" void kernel_launch(void* const* d_in, const int* in_sizes, int n_in,
                              void* d_out, int out_size, void* d_ws, size_t ws_size,
                              hipStream_t stream) {
    const float* imgs = reinterpret_cast<const float*>(d_in[0]);
    const float* caps = reinterpret_cast<const float*>(d_in[1]);

    float* diag     = reinterpret_cast<float*>(d_ws);
    unsigned* rowmax = reinterpret_cast<unsigned*>(diag + NN);
    unsigned* colmax = rowmax + NN;
    short* imgsb    = reinterpret_cast<short*>(colmax + NN);
    short* capsb    = imgsb + (size_t)NN * DD;

    fused_prep_kernel<<<NN / 4, 256, 0, stream>>>(imgs, caps, imgsb, capsb,
                                                  diag, rowmax, colmax);

    score_max_kernel<<<512, 256, 0, stream>>>(imgsb, capsb, diag,
                                              rowmax, colmax);

    finalize_kernel<<<1, 256, 0, stream>>>(diag, rowmax, colmax,
                                           reinterpret_cast<float*>(d_out));
}

// Round 7
// 167.778 us; speedup vs baseline: 1.7250x; 1.0203x over previous
//
#include <hip/hip_runtime.h>
#include <hip/hip_bf16.h>
#include <stdint.h>
#include <math.h>

#define NN 16384
#define DD 256
#define MARGIN_F 0.2f

typedef __attribute__((ext_vector_type(8))) short bf16x8;
typedef __attribute__((ext_vector_type(4))) float f32x4;

__device__ inline short f2bf(float f) {
    __hip_bfloat16 h = __float2bfloat16(f);
    return *reinterpret_cast<short*>(&h);
}

// monotone order-preserving float<->uint key (max via unsigned atomicMax)
__device__ inline unsigned fkey(float f) {
    unsigned b = __float_as_uint(f);
    return (b & 0x80000000u) ? ~b : (b | 0x80000000u);
}
__device__ inline float fdec(unsigned k) {
    return __uint_as_float((k & 0x80000000u) ? (k ^ 0x80000000u) : ~k);
}
#define NEG_INF_KEY 0x007FFFFFu   // fkey(-inf)

__device__ inline void gload16(const void* g, void* l) {
    __builtin_amdgcn_global_load_lds(
        (const __attribute__((address_space(1))) void*)g,
        (__attribute__((address_space(3))) void*)l, 16, 0, 0);
}

// ---------------- fused prep: f32->bf16 + diag + init maxes ----------------
__global__ __launch_bounds__(256) void fused_prep_kernel(
    const float* __restrict__ imgs, const float* __restrict__ caps,
    short* __restrict__ imgsb, short* __restrict__ capsb,
    float* __restrict__ diag, unsigned* __restrict__ rowmax,
    unsigned* __restrict__ colmax) {
    const int i = (blockIdx.x << 2) + (threadIdx.x >> 6);
    const int l = threadIdx.x & 63;
    const float4* a4 = reinterpret_cast<const float4*>(imgs + (size_t)i * DD);
    const float4* b4 = reinterpret_cast<const float4*>(caps + (size_t)i * DD);
    float4 av = a4[l];
    float4 bv = b4[l];
    short4 as, bs;
    as.x = f2bf(av.x); as.y = f2bf(av.y); as.z = f2bf(av.z); as.w = f2bf(av.w);
    bs.x = f2bf(bv.x); bs.y = f2bf(bv.y); bs.z = f2bf(bv.z); bs.w = f2bf(bv.w);
    reinterpret_cast<short4*>(imgsb + (size_t)i * DD)[l] = as;
    reinterpret_cast<short4*>(capsb + (size_t)i * DD)[l] = bs;
    float s = av.x * bv.x + av.y * bv.y + av.z * bv.z + av.w * bv.w;
    #pragma unroll
    for (int off = 32; off > 0; off >>= 1) s += __shfl_down(s, off);
    if (l == 0) {
        diag[i] = s;
        rowmax[i] = NEG_INF_KEY;
        colmax[i] = NEG_INF_KEY;
    }
}

// ---------------- main: A-resident strip kernel, pipelined chunks ----------
// 512 blocks = 128 row-panels x 4 col-strips. A panel (128x256) -> registers.
// Per 64-col chunk: barrier -> issue stage(h+1) -> vmcnt(8) (stage(h) done,
// stage(h+1) stays in flight across the whole chunk) -> barrier -> register-
// double-buffered ks-loop: ds_reads for ks+1 issue BEFORE MFMAs of ks, so the
// LDS pipe streams under the MFMA bursts (compiler inserts counted lgkmcnt).
__global__ __launch_bounds__(256, 2) void score_max_kernel(
    const short* __restrict__ imgsb, const short* __restrict__ capsb,
    const float* __restrict__ diag,
    unsigned* __restrict__ rowmax, unsigned* __restrict__ colmax) {

    __shared__ char lds[81920];   // [0,64K): A then 2x32KB B bufs; [64K,80K): colmax keys
    unsigned* clds = reinterpret_cast<unsigned*>(lds + 65536);

    const int bid   = blockIdx.x;
    const int panel = bid >> 2;
    const int strip = bid & 3;
    const int brow  = panel << 7;
    const int scol  = strip << 12;

    const int t    = threadIdx.x;
    const int wid  = t >> 6;
    const int lane = t & 63;
    const int wr   = wid >> 1;
    const int wc   = wid & 1;
    const int rg   = lane >> 4;
    const int cl   = lane & 15;

    // ---- init colmax keys ----
    #pragma unroll
    for (int i = 0; i < 16; ++i) clds[t + (i << 8)] = NEG_INF_KEY;

    // ---- stage A panel (64KB), chunk-swizzled ----
    {
        const int cs = t & 31;
        const int r0 = t >> 5;
        const int co = ((cs ^ (r0 & 7)) << 3);
        const short* src = imgsb + (((size_t)(brow + r0)) << 8) + co;
        #pragma unroll
        for (int i = 0; i < 16; ++i)
            gload16(src + ((size_t)i << 11), lds + t * 16 + i * 4096);
    }
    __syncthreads();

    // ---- A fragments to registers: af[m][ks] ----
    bf16x8 af[4][8];
    #pragma unroll
    for (int m = 0; m < 4; ++m) {
        const int row = wr * 64 + m * 16 + cl;
        const char* rb = lds + row * 512;
        const int sw = row & 7;
        #pragma unroll
        for (int ks = 0; ks < 8; ++ks) {
            const int k8 = (ks << 2) + rg;
            af[m][ks] = *reinterpret_cast<const bf16x8*>(rb + ((k8 ^ sw) << 4));
        }
    }
    __syncthreads();   // done reading A before B overwrites

    // ---- B staging geometry ----
    const int br0 = t >> 5;
    const int bco = (((t & 31) ^ (br0 & 7)) << 3);

    #define STAGEB(bo, cb) {                                                   \
        const short* s_ = capsb + (((size_t)((cb) + br0)) << 8) + bco;         \
        _Pragma("unroll")                                                      \
        for (int i_ = 0; i_ < 8; ++i_)                                         \
            gload16(s_ + ((size_t)i_ << 11), lds + (bo) + t * 16 + i_ * 4096); \
    }

    // prologue: issue stage(0) into buf0 (completion enforced at h=0 top)
    STAGEB(0, scol);

    float rmx[4][4];
    #pragma unroll
    for (int m = 0; m < 4; ++m)
        #pragma unroll
        for (int r = 0; r < 4; ++r) rmx[m][r] = -INFINITY;

    const int rr0 = wc * 32 + cl;       // B row for n=0
    const int rr1 = rr0 + 16;           // B row for n=1
    const int sw0 = rr0 & 7;
    const int sw1 = rr1 & 7;

    for (int h = 0; h < 64; ++h) {
        const int cb = scol + (h << 6);
        const char* cur = lds + ((h & 1) << 15);

        // barrier 1: all waves done reading buf[(h+1)&1] (chunk h-1)
        __builtin_amdgcn_s_barrier();
        asm volatile("" ::: "memory");
        if (h < 63) {
            STAGEB(((h + 1) & 1) << 15, cb + 64);
            // oldest-beyond-8 = stage(h): wait it; stage(h+1) stays in flight
            asm volatile("s_waitcnt vmcnt(8)" ::: "memory");
        } else {
            asm volatile("s_waitcnt vmcnt(0)" ::: "memory");
        }
        // barrier 2: stage(h) visible to all waves
        __builtin_amdgcn_s_barrier();
        asm volatile("" ::: "memory");

        f32x4 acc[4][2];
        #pragma unroll
        for (int m = 0; m < 4; ++m) {
            acc[m][0] = (f32x4){0.f, 0.f, 0.f, 0.f};
            acc[m][1] = (f32x4){0.f, 0.f, 0.f, 0.f};
        }

        // ---- register-double-buffered fragment pipeline ----
        bf16x8 fb0[2], fb1[2];
        fb0[0] = *reinterpret_cast<const bf16x8*>(
            cur + rr0 * 512 + ((rg ^ sw0) << 4));
        fb1[0] = *reinterpret_cast<const bf16x8*>(
            cur + rr1 * 512 + ((rg ^ sw1) << 4));

        #pragma unroll
        for (int ks = 0; ks < 8; ++ks) {
            const int pcur = ks & 1;
            const int pnxt = pcur ^ 1;
            if (ks < 7) {
                const int k8n = ((ks + 1) << 2) + rg;
                fb0[pnxt] = *reinterpret_cast<const bf16x8*>(
                    cur + rr0 * 512 + ((k8n ^ sw0) << 4));
                fb1[pnxt] = *reinterpret_cast<const bf16x8*>(
                    cur + rr1 * 512 + ((k8n ^ sw1) << 4));
            }
            __builtin_amdgcn_s_setprio(1);
            #pragma unroll
            for (int m = 0; m < 4; ++m)
                acc[m][0] = __builtin_amdgcn_mfma_f32_16x16x32_bf16(
                    af[m][ks], fb0[pcur], acc[m][0], 0, 0, 0);
            #pragma unroll
            for (int m = 0; m < 4; ++m)
                acc[m][1] = __builtin_amdgcn_mfma_f32_16x16x32_bf16(
                    af[m][ks], fb1[pcur], acc[m][1], 0, 0, 0);
            __builtin_amdgcn_s_setprio(0);
        }

        // ---- diagonal fix (at most 2 chunks per block) ----
        if (cb < brow + 128 && cb + 64 > brow) {
            #pragma unroll
            for (int m = 0; m < 4; ++m)
                #pragma unroll
                for (int r = 0; r < 4; ++r) {
                    const int i = brow + wr * 64 + m * 16 + (rg << 2) + r;
                    const int d = i - cb - wc * 32;
                    #pragma unroll
                    for (int n = 0; n < 2; ++n)
                        if (d == n * 16 + cl) acc[m][n][r] = -diag[i];
                }
        }

        // ---- running row-max (registers) ----
        #pragma unroll
        for (int m = 0; m < 4; ++m)
            #pragma unroll
            for (int r = 0; r < 4; ++r)
                rmx[m][r] = fmaxf(rmx[m][r],
                                  fmaxf(acc[m][0][r], acc[m][1][r]));

        // ---- col-max -> LDS keys ----
        #pragma unroll
        for (int n = 0; n < 2; ++n) {
            float v = acc[0][n][0];
            #pragma unroll
            for (int m = 0; m < 4; ++m)
                #pragma unroll
                for (int r = 0; r < 4; ++r)
                    v = fmaxf(v, acc[m][n][r]);
            v = fmaxf(v, __shfl_xor(v, 16));
            v = fmaxf(v, __shfl_xor(v, 32));
            if (rg == 0)
                atomicMax(&clds[(h << 6) + wc * 32 + n * 16 + cl], fkey(v));
        }
    }

    // ---- flush colmax keys to global ----
    __syncthreads();
    #pragma unroll
    for (int i = 0; i < 16; ++i) {
        const int c = t + (i << 8);
        atomicMax(&colmax[scol + c], clds[c]);
    }

    // ---- row-max writeout ----
    #pragma unroll
    for (int m = 0; m < 4; ++m)
        #pragma unroll
        for (int r = 0; r < 4; ++r) {
            float v = rmx[m][r];
            v = fmaxf(v, __shfl_xor(v, 1));
            v = fmaxf(v, __shfl_xor(v, 2));
            v = fmaxf(v, __shfl_xor(v, 4));
            v = fmaxf(v, __shfl_xor(v, 8));
            if (cl == 0)
                atomicMax(&rowmax[brow + wr * 64 + m * 16 + (rg << 2) + r],
                          fkey(v));
        }
    #undef STAGEB
}

// ---------------- finalize: hinge + total sum ----------------
__global__ void finalize_kernel(const float* __restrict__ diag,
                                const unsigned* __restrict__ rowmax,
                                const unsigned* __restrict__ colmax,
                                float* __restrict__ out) {
    __shared__ float red[256];
    int t = threadIdx.x;
    float s = 0.f;
    for (int idx = t; idx < 2 * NN; idx += 256) {
        int i = idx & (NN - 1);
        float mx = fdec((idx < NN) ? colmax[i] : rowmax[i]);
        s += fmaxf(mx + (MARGIN_F - diag[i]), 0.f);
    }
    red[t] = s;
    __syncthreads();
    for (int off = 128; off > 0; off >>= 1) {
        if (t < off) red[t] += red[t + off];
        __syncthreads();
    }
    if (t == 0) out[0] = red[0];
}

extern "C" void kernel_launch(void* const* d_in, const int* in_sizes, int n_in,
                              void* d_out, int out_size, void* d_ws, size_t ws_size,
                              hipStream_t stream) {
    const float* imgs = reinterpret_cast<const float*>(d_in[0]);
    const float* caps = reinterpret_cast<const float*>(d_in[1]);

    float* diag      = reinterpret_cast<float*>(d_ws);
    unsigned* rowmax = reinterpret_cast<unsigned*>(diag + NN);
    unsigned* colmax = rowmax + NN;
    short* imgsb     = reinterpret_cast<short*>(colmax + NN);
    short* capsb     = imgsb + (size_t)NN * DD;

    fused_prep_kernel<<<NN / 4, 256, 0, stream>>>(imgs, caps, imgsb, capsb,
                                                  diag, rowmax, colmax);

    score_max_kernel<<<512, 256, 0, stream>>>(imgsb, capsb, diag,
                                              rowmax, colmax);

    finalize_kernel<<<1, 256, 0, stream>>>(diag, rowmax, colmax,
                                           reinterpret_cast<float*>(d_out));
}